// Round 5
// baseline (318.120 us; speedup 1.0000x reference)
//
#include <hip/hip_runtime.h>

#define IN_DIM 4096
#define OUT_DIM 4096
#define M_DIM 8192
#define RANK 32
#define BK 64
#define NT (IN_DIM / BK)   // 64 K-tiles

typedef __bf16 bf16x8 __attribute__((ext_vector_type(8)));
typedef float f32x4 __attribute__((ext_vector_type(4)));
typedef float f32x16 __attribute__((ext_vector_type(16)));

__device__ __forceinline__ unsigned short f2bf(float f) {
  unsigned u = __builtin_bit_cast(unsigned, f);
  u += 0x7FFF + ((u >> 16) & 1);   // round-to-nearest-even
  return (unsigned short)(u >> 16);
}

// ---------------- fused prep: blocks [0,1024) do Wb, [1024,1536) do Xb ----------------
// Wb = bf16(W + A @ B^T) via rank-32 MFMA (one 16x16x32 per fragment, K=32 exact).
// Xb = bf16(x). Merged so the two BW-bound phases overlap on the device.
__global__ __launch_bounds__(256) void prep_kernel(
    const float* __restrict__ X, unsigned short* __restrict__ Xb,
    const float* __restrict__ W, const float* __restrict__ A,
    const float* __restrict__ B, unsigned short* __restrict__ Wb) {
  const int tid = threadIdx.x;
  if (blockIdx.x >= 1024) {
    // ---- X cast path ----
    const int idx0 = (blockIdx.x - 1024) * 256 + tid;
    const int stride = 512 * 256;
    const int total4 = (M_DIM * IN_DIM) / 4;
    for (int i = idx0; i < total4; i += stride) {
      const float4 v = reinterpret_cast<const float4*>(X)[i];
      ushort4 o;
      o.x = f2bf(v.x); o.y = f2bf(v.y); o.z = f2bf(v.z); o.w = f2bf(v.w);
      reinterpret_cast<ushort4*>(Xb)[i] = o;
    }
    return;
  }
  // ---- W path ----
  __shared__ unsigned short sA[128][40];
  __shared__ unsigned short sB[128][40];
  const int lane = tid & 63;
  const int wid  = tid >> 6;
  const int wr   = wid >> 1, wc = wid & 1;
  const int li   = lane & 15, kg = lane >> 4;
  const int bRow = (blockIdx.x >> 5) * 128;   // out dim
  const int bCol = (blockIdx.x & 31) * 128;   // in dim

  for (int i = tid; i < 128 * 8; i += 256) {
    const int r = i >> 3, q = i & 7;
    const float4 va = reinterpret_cast<const float4*>(A + (size_t)(bRow + r) * RANK)[q];
    ushort4 oa;
    oa.x = f2bf(va.x); oa.y = f2bf(va.y); oa.z = f2bf(va.z); oa.w = f2bf(va.w);
    *reinterpret_cast<ushort4*>(&sA[r][q * 4]) = oa;
    const float4 vb = reinterpret_cast<const float4*>(B + (size_t)(bCol + r) * RANK)[q];
    ushort4 ob;
    ob.x = f2bf(vb.x); ob.y = f2bf(vb.y); ob.z = f2bf(vb.z); ob.w = f2bf(vb.w);
    *reinterpret_cast<ushort4*>(&sB[r][q * 4]) = ob;
  }
  __syncthreads();

  bf16x8 af[4], bq[4];
#pragma unroll
  for (int m = 0; m < 4; ++m)
    af[m] = *reinterpret_cast<const bf16x8*>(&sA[wr * 64 + m * 16 + li][kg * 8]);
#pragma unroll
  for (int n = 0; n < 4; ++n)
    bq[n] = *reinterpret_cast<const bf16x8*>(&sB[wc * 64 + n * 16 + li][kg * 8]);

  f32x4 acc[4][4];
#pragma unroll
  for (int m = 0; m < 4; ++m)
#pragma unroll
    for (int n = 0; n < 4; ++n) {
      acc[m][n] = f32x4{0.f, 0.f, 0.f, 0.f};
      acc[m][n] = __builtin_amdgcn_mfma_f32_16x16x32_bf16(af[m], bq[n], acc[m][n], 0, 0, 0);
    }

#pragma unroll
  for (int m = 0; m < 4; ++m) {
#pragma unroll
    for (int n = 0; n < 4; ++n) {
      const int col = bCol + wc * 64 + n * 16 + li;
#pragma unroll
      for (int j = 0; j < 4; ++j) {
        const int row = bRow + wr * 64 + m * 16 + kg * 4 + j;
        const size_t idx = (size_t)row * IN_DIM + col;
        Wb[idx] = f2bf(W[idx] + acc[m][n][j]);
      }
    }
  }
}

// ---------------- main GEMM: 256x256 tile, BK=64, 8-phase counted-vmcnt ----------------
// 8 waves (2M x 4N), per-wave 128x64 output. MFMA = 32x32x16 bf16 (99.8%-of-peak
// shape, m119) : per wave 4x2 frags x 4 k-steps = 32 MFMA/tile (was 64 of 16x16x32).
// LDS 128 KiB: lds[8][8192] shorts; region q = dbuf*4 + op*2 + half (16 KiB each).
// Region local rows: A half h: lr = wr*64 + mq*32 + (lane&31) (global wr*128+h*64+...);
//                    B half h: lr = wc*32 + (lane&31)         (global wc*64+h*32+...).
// Chunk swizzle: 16B chunk kc of row r stored at kc^(r&7); frag read chunk
// kc = ks*2 + (lane>>5) -> per 16-lane phase group 8 distinct slots x2 rows (free).
// Phase schedule per tile t (dbuf d=t&1):
//   ph0: stage B1(t+1)->d^1 | read A0(8)+B0(4) | BAR | prio MM(0,0) | BAR
//   ph1: stage A0(t+2)->d   | read B1(4)       | BAR | prio MM(0,1) | BAR
//   ph2: stage B0(t+2)->d   | read A1(8)       | BAR | prio MM(1,0) | BAR
//   ph3: stage A1(t+2)->d   |                  | BAR | prio MM(1,1) | vmcnt(6) BAR
// Steady state: 3 half-tiles (6 loads) in flight across the tile boundary.
__global__ __launch_bounds__(512, 2) void gemm_kernel(
    const unsigned short* __restrict__ Xb, const unsigned short* __restrict__ Wb,
    const float* __restrict__ bias, float* __restrict__ Y) {
  __shared__ unsigned short lds[8][8192];   // 128 KiB
  const int tid  = threadIdx.x;
  const int lane = tid & 63;
  const int wid  = tid >> 6;          // 0..7
  const int wr   = wid >> 2;          // 0..1
  const int wc   = wid & 3;           // 0..3
  const int l31  = lane & 31;
  const int hf   = lane >> 5;
  const int l7   = lane & 7;

  // XCD-aware bijective swizzle: 512 blocks = 8 XCDs x 64
  const int bid = blockIdx.x;
  const int swz = (bid & 7) * 64 + (bid >> 3);
  const int bx  = swz & 15;           // N tiles: 4096/256 = 16
  const int by  = swz >> 4;           // M tiles: 8192/256 = 32
  const int bRow = by * 256, bCol = bx * 256;

  // ---- staging source addresses (per thread, per half h, per sub-load l) ----
  // physical chunk p = l*512 + tid; local row r = p>>3; kc = (p&7)^(r&7)
  const int kcS = (tid & 7) ^ ((tid >> 3) & 7);
  const unsigned short* srcA[2][2];
  const unsigned short* srcB[2][2];
#pragma unroll
  for (int h = 0; h < 2; ++h)
#pragma unroll
    for (int l = 0; l < 2; ++l) {
      const int gA = l * 128 + h * 64 + (tid >> 3);
      const int gB = (l * 2 + (tid >> 8)) * 64 + h * 32 + ((tid >> 3) & 31);
      srcA[h][l] = Xb + (size_t)(bRow + gA) * IN_DIM + kcS * 8;
      srcB[h][l] = Wb + (size_t)(bCol + gB) * IN_DIM + kcS * 8;
    }
  char* const ldsRaw = (char*)&lds[0][0];

#define GLD(src, dstoff)                                                       \
  __builtin_amdgcn_global_load_lds(                                            \
      (const __attribute__((address_space(1))) unsigned int*)(src),            \
      (__attribute__((address_space(3))) unsigned int*)(ldsRaw + (dstoff)),    \
      16, 0, 0)
#define STAGE_A(s, h)                                                          \
  do {                                                                         \
    const int q_ = (((s) & 1) << 2) + (h);                                     \
    GLD(srcA[h][0] + (s) * BK, q_ * 16384 + tid * 16);                         \
    GLD(srcA[h][1] + (s) * BK, q_ * 16384 + 8192 + tid * 16);                  \
  } while (0)
#define STAGE_B(s, h)                                                          \
  do {                                                                         \
    const int q_ = (((s) & 1) << 2) + 2 + (h);                                 \
    GLD(srcB[h][0] + (s) * BK, q_ * 16384 + tid * 16);                         \
    GLD(srcB[h][1] + (s) * BK, q_ * 16384 + 8192 + tid * 16);                  \
  } while (0)
#define BAR() __builtin_amdgcn_s_barrier()

  // ---- fragment read addressing ----
  const int rowAoff = (wr * 64 + l31) * 64;   // shorts
  const int rowBoff = (wc * 32 + l31) * 64;
  int kxx[4];
#pragma unroll
  for (int ks = 0; ks < 4; ++ks) kxx[ks] = ((ks * 2 + hf) ^ l7) * 8;

  bf16x8 af[2][4], bq[2][4];
  f32x16 acc[4][2];
#pragma unroll
  for (int m = 0; m < 4; ++m)
#pragma unroll
    for (int n = 0; n < 2; ++n)
#pragma unroll
      for (int j = 0; j < 16; ++j) acc[m][n][j] = 0.f;

#define RD_A(ms_)                                                              \
  do {                                                                         \
    const unsigned short* b_ = &lds[(dcur << 2) + (ms_)][0] + rowAoff;         \
    _Pragma("unroll") for (int mq = 0; mq < 2; ++mq)                           \
      _Pragma("unroll") for (int ks = 0; ks < 4; ++ks)                         \
        af[mq][ks] =                                                           \
            *reinterpret_cast<const bf16x8*>(b_ + mq * 2048 + kxx[ks]);        \
  } while (0)
#define RD_B(ns_)                                                              \
  do {                                                                         \
    const unsigned short* b_ = &lds[(dcur << 2) + 2 + (ns_)][0] + rowBoff;     \
    _Pragma("unroll") for (int ks = 0; ks < 4; ++ks)                           \
      bq[ns_][ks] = *reinterpret_cast<const bf16x8*>(b_ + kxx[ks]);            \
  } while (0)
#define MM(ms_, ns_)                                                           \
  do {                                                                         \
    __builtin_amdgcn_s_setprio(1);                                             \
    _Pragma("unroll") for (int mq = 0; mq < 2; ++mq)                           \
      _Pragma("unroll") for (int ks = 0; ks < 4; ++ks)                         \
        acc[(ms_) * 2 + mq][ns_] = __builtin_amdgcn_mfma_f32_32x32x16_bf16(    \
            af[mq][ks], bq[ns_][ks], acc[(ms_) * 2 + mq][ns_], 0, 0, 0);       \
    __builtin_amdgcn_s_setprio(0);                                             \
  } while (0)

  // ---- prologue: tile 0 fully + A0,B0,A1 of tile 1 (B1(1) staged at t=0 ph0)
  STAGE_A(0, 0); STAGE_A(0, 1); STAGE_B(0, 0); STAGE_B(0, 1);
  STAGE_A(1, 0); STAGE_B(1, 0); STAGE_A(1, 1);
  asm volatile("s_waitcnt vmcnt(6)" ::: "memory");   // drain tile 0's 8 loads
  BAR();

  for (int t = 0; t < NT; ++t) {
    const int dcur = t & 1;
    const bool st1 = (t + 1 < NT), st2 = (t + 2 < NT);
    // ph0
    if (st1) STAGE_B(t + 1, 1);
    RD_A(0); RD_B(0);
    BAR();
    MM(0, 0);
    BAR();
    // ph1
    if (st2) STAGE_A(t + 2, 0);
    RD_B(1);
    BAR();
    MM(0, 1);
    BAR();
    // ph2
    if (st2) STAGE_B(t + 2, 0);
    RD_A(1);
    BAR();
    MM(1, 0);
    BAR();
    // ph3
    if (st2) STAGE_A(t + 2, 1);
    BAR();
    MM(1, 1);
    if (st2) asm volatile("s_waitcnt vmcnt(6)" ::: "memory");
    else     asm volatile("s_waitcnt vmcnt(0)" ::: "memory");
    BAR();
  }
#undef GLD
#undef STAGE_A
#undef STAGE_B
#undef RD_A
#undef RD_B
#undef MM
#undef BAR

  // ---- epilogue: 32x32 C/D layout (m74/m101): col = lane&31,
  //      row = (reg&3) + 8*(reg>>2) + 4*(lane>>5) ----
#pragma unroll
  for (int nf = 0; nf < 2; ++nf) {
    const int col = bCol + wc * 64 + nf * 32 + l31;
    const float bv = bias[col];
#pragma unroll
    for (int mf = 0; mf < 4; ++mf) {
      const int rbase = bRow + wr * 128 + mf * 32 + hf * 4;
#pragma unroll
      for (int j = 0; j < 16; ++j) {
        const int row = rbase + (j & 3) + 8 * (j >> 2);
        Y[(size_t)row * OUT_DIM + col] = acc[mf][nf][j] + bv;
      }
    }
  }
}

extern "C" void kernel_launch(void* const* d_in, const int* in_sizes, int n_in,
                              void* d_out, int out_size, void* d_ws, size_t ws_size,
                              hipStream_t stream) {
  const float* x    = (const float*)d_in[0];
  const float* w    = (const float*)d_in[1];
  const float* bias = (const float*)d_in[2];
  const float* A    = (const float*)d_in[3];
  const float* B    = (const float*)d_in[4];
  float* y = (float*)d_out;

  const size_t xb_bytes = (size_t)M_DIM * IN_DIM * 2;          // 64 MiB
  const size_t wb_bytes = (size_t)OUT_DIM * IN_DIM * 2;        // 32 MiB
  if (ws_size < xb_bytes + wb_bytes) return;

  unsigned short* Xb = (unsigned short*)d_ws;
  unsigned short* Wb = (unsigned short*)((char*)d_ws + xb_bytes);

  prep_kernel<<<1536, 256, 0, stream>>>(x, Xb, w, A, B, Wb);
  gemm_kernel<<<(M_DIM / 256) * (OUT_DIM / 256), 512, 0, stream>>>(Xb, Wb, bias, y);
}

// Round 6
// 277.976 us; speedup vs baseline: 1.1444x; 1.1444x over previous
//
#include <hip/hip_runtime.h>

#define IN_DIM 4096
#define OUT_DIM 4096
#define M_DIM 8192
#define RANK 32
#define BK 64
#define NT (IN_DIM / BK)   // 64 K-tiles

typedef __bf16 bf16x8 __attribute__((ext_vector_type(8)));
typedef float f32x4 __attribute__((ext_vector_type(4)));

__device__ __forceinline__ unsigned short f2bf(float f) {
  unsigned u = __builtin_bit_cast(unsigned, f);
  u += 0x7FFF + ((u >> 16) & 1);   // round-to-nearest-even
  return (unsigned short)(u >> 16);
}

// ---------------- fused prep: blocks [0,1024) do Wb, [1024,1536) do Xb ----------------
__global__ __launch_bounds__(256) void prep_kernel(
    const float* __restrict__ X, unsigned short* __restrict__ Xb,
    const float* __restrict__ W, const float* __restrict__ A,
    const float* __restrict__ B, unsigned short* __restrict__ Wb) {
  const int tid = threadIdx.x;
  if (blockIdx.x >= 1024) {
    // ---- X cast path ----
    const int idx0 = (blockIdx.x - 1024) * 256 + tid;
    const int stride = 512 * 256;
    const int total4 = (M_DIM * IN_DIM) / 4;
    for (int i = idx0; i < total4; i += stride) {
      const float4 v = reinterpret_cast<const float4*>(X)[i];
      ushort4 o;
      o.x = f2bf(v.x); o.y = f2bf(v.y); o.z = f2bf(v.z); o.w = f2bf(v.w);
      reinterpret_cast<ushort4*>(Xb)[i] = o;
    }
    return;
  }
  // ---- W path: Wb = bf16(W + A @ B^T), rank-32 via one MFMA per fragment ----
  __shared__ unsigned short sA[128][40];
  __shared__ unsigned short sB[128][40];
  const int lane = tid & 63;
  const int wid  = tid >> 6;
  const int wr   = wid >> 1, wc = wid & 1;
  const int li   = lane & 15, kg = lane >> 4;
  const int bRow = (blockIdx.x >> 5) * 128;   // out dim
  const int bCol = (blockIdx.x & 31) * 128;   // in dim

  for (int i = tid; i < 128 * 8; i += 256) {
    const int r = i >> 3, q = i & 7;
    const float4 va = reinterpret_cast<const float4*>(A + (size_t)(bRow + r) * RANK)[q];
    ushort4 oa;
    oa.x = f2bf(va.x); oa.y = f2bf(va.y); oa.z = f2bf(va.z); oa.w = f2bf(va.w);
    *reinterpret_cast<ushort4*>(&sA[r][q * 4]) = oa;
    const float4 vb = reinterpret_cast<const float4*>(B + (size_t)(bCol + r) * RANK)[q];
    ushort4 ob;
    ob.x = f2bf(vb.x); ob.y = f2bf(vb.y); ob.z = f2bf(vb.z); ob.w = f2bf(vb.w);
    *reinterpret_cast<ushort4*>(&sB[r][q * 4]) = ob;
  }
  __syncthreads();

  bf16x8 af[4], bq[4];
#pragma unroll
  for (int m = 0; m < 4; ++m)
    af[m] = *reinterpret_cast<const bf16x8*>(&sA[wr * 64 + m * 16 + li][kg * 8]);
#pragma unroll
  for (int n = 0; n < 4; ++n)
    bq[n] = *reinterpret_cast<const bf16x8*>(&sB[wc * 64 + n * 16 + li][kg * 8]);

  f32x4 acc[4][4];
#pragma unroll
  for (int m = 0; m < 4; ++m)
#pragma unroll
    for (int n = 0; n < 4; ++n) {
      acc[m][n] = f32x4{0.f, 0.f, 0.f, 0.f};
      acc[m][n] = __builtin_amdgcn_mfma_f32_16x16x32_bf16(af[m], bq[n], acc[m][n], 0, 0, 0);
    }

#pragma unroll
  for (int m = 0; m < 4; ++m) {
#pragma unroll
    for (int n = 0; n < 4; ++n) {
      const int col = bCol + wc * 64 + n * 16 + li;
#pragma unroll
      for (int j = 0; j < 4; ++j) {
        const int row = bRow + wr * 64 + m * 16 + kg * 4 + j;
        const size_t idx = (size_t)row * IN_DIM + col;
        Wb[idx] = f2bf(W[idx] + acc[m][n][j]);
      }
    }
  }
}

// ---------------- main GEMM: 256x256 tile, BK=64, 4-phase, ONE barrier/phase ----------------
// 8 waves (2M x 4N), per-wave 128x64, 16x16x32 MFMA (round-4 proven 0-conflict reads).
// One BAR per phase (pre-MM) -> waves slip by one MM cluster, so one wave's
// ds_reads/stage-issues overlap other waves' MFMA (cross-wave pipe overlap).
// WAR safety rule: a stage-write to region R must be >=1 barrier AFTER the MM
// that lgkm-waits R's last read (in-order LDS completion per wave). Schedule:
//   ph0: [st1: STAGE_B(t+1,1); STAGE_A(t+1,1)] RD_A(0),RD_B(0) | BAR | MM(0,0)
//   ph1:                                        RD_B(1)         | BAR | MM(0,1)
//   ph2: [st2: STAGE_A(t+2,0)]                  RD_A(1)         | BAR | MM(1,0)
//   ph3: [st2: STAGE_B(t+2,0)] vmcnt(4)                         | BAR | MM(1,1)
//   - B1/A1(t+1)->(d^1): last reads at t-1.ph1/ph2, >=2 BARs back  -> safe
//   - A0(t+2)->(d,A0): read t.ph0, MM(0,0); stage is post-BAR1     -> safe
//   - B0(t+2)->(d,B0): read t.ph0, MM(0,0); stage is post-BAR2     -> safe
// vmcnt induction: 8 issued/tile, queue at ph3 = 4(prev)+8 = 12; vmcnt(4)
// retires exactly tile t+1's 8 loads {A0,B0 (t-1.ph2/3... prologue), B1,A1}.
__global__ __launch_bounds__(512, 2) void gemm_kernel(
    const unsigned short* __restrict__ Xb, const unsigned short* __restrict__ Wb,
    const float* __restrict__ bias, float* __restrict__ Y) {
  __shared__ unsigned short lds[8][8192];   // 128 KiB
  const int tid  = threadIdx.x;
  const int lane = tid & 63;
  const int wid  = tid >> 6;          // 0..7
  const int wr   = wid >> 2;          // 0..1
  const int wc   = wid & 3;           // 0..3
  const int li   = lane & 15, kg = lane >> 4;

  // XCD-aware bijective swizzle: 512 blocks = 8 XCDs x 64
  const int bid = blockIdx.x;
  const int swz = (bid & 7) * 64 + (bid >> 3);
  const int bx  = swz & 15;           // N tiles: 4096/256 = 16
  const int by  = swz >> 4;           // M tiles: 8192/256 = 32
  const int bRow = by * 256, bCol = bx * 256;

  // ---- staging source addresses: physical chunk p = l*512 + tid;
  //      local row r = p>>3; kc = (p&7)^(r&7)  (XOR chunk swizzle) ----
  const int kcS = (tid & 7) ^ ((tid >> 3) & 7);
  const unsigned short* srcA[2][2];
  const unsigned short* srcB[2][2];
#pragma unroll
  for (int h = 0; h < 2; ++h)
#pragma unroll
    for (int l = 0; l < 2; ++l) {
      const int gA = l * 128 + h * 64 + (tid >> 3);
      const int gB = (l * 2 + (tid >> 8)) * 64 + h * 32 + ((tid >> 3) & 31);
      srcA[h][l] = Xb + (size_t)(bRow + gA) * IN_DIM + kcS * 8;
      srcB[h][l] = Wb + (size_t)(bCol + gB) * IN_DIM + kcS * 8;
    }
  char* const ldsRaw = (char*)&lds[0][0];

#define GLD(src, dstoff)                                                       \
  __builtin_amdgcn_global_load_lds(                                            \
      (const __attribute__((address_space(1))) unsigned int*)(src),            \
      (__attribute__((address_space(3))) unsigned int*)(ldsRaw + (dstoff)),    \
      16, 0, 0)
#define STAGE_A(s, h)                                                          \
  do {                                                                         \
    const int q_ = (((s) & 1) << 2) + (h);                                     \
    GLD(srcA[h][0] + (s) * BK, q_ * 16384 + tid * 16);                         \
    GLD(srcA[h][1] + (s) * BK, q_ * 16384 + 8192 + tid * 16);                  \
  } while (0)
#define STAGE_B(s, h)                                                          \
  do {                                                                         \
    const int q_ = (((s) & 1) << 2) + 2 + (h);                                 \
    GLD(srcB[h][0] + (s) * BK, q_ * 16384 + tid * 16);                         \
    GLD(srcB[h][1] + (s) * BK, q_ * 16384 + 8192 + tid * 16);                  \
  } while (0)
#define BAR() __builtin_amdgcn_s_barrier()

  // ---- fragment read addressing (round-4 proven conflict-free) ----
  const int rowAoff = (wr * 64 + li) * 64;
  const int rowBoff = (wc * 32 + li) * 64;
  int kx[2];
  kx[0] = ((0 * 4 + kg) ^ (li & 7)) * 8;
  kx[1] = ((1 * 4 + kg) ^ (li & 7)) * 8;

  bf16x8 af[4][2], bq[4][2];
  f32x4 acc[8][4];
#pragma unroll
  for (int m = 0; m < 8; ++m)
#pragma unroll
    for (int n = 0; n < 4; ++n) acc[m][n] = f32x4{0.f, 0.f, 0.f, 0.f};

#define RD_A(ms_)                                                              \
  do {                                                                         \
    const unsigned short* b_ = &lds[(dcur << 2) + (ms_)][0] + rowAoff;         \
    _Pragma("unroll") for (int mq = 0; mq < 4; ++mq)                           \
      _Pragma("unroll") for (int ks = 0; ks < 2; ++ks)                         \
        af[mq][ks] =                                                           \
            *reinterpret_cast<const bf16x8*>(b_ + mq * 1024 + kx[ks]);         \
  } while (0)
#define RD_B(ns_)                                                              \
  do {                                                                         \
    const unsigned short* b_ = &lds[(dcur << 2) + 2 + (ns_)][0] + rowBoff;     \
    _Pragma("unroll") for (int nq = 0; nq < 2; ++nq)                           \
      _Pragma("unroll") for (int ks = 0; ks < 2; ++ks)                         \
        bq[(ns_) * 2 + nq][ks] =                                               \
            *reinterpret_cast<const bf16x8*>(b_ + nq * 1024 + kx[ks]);         \
  } while (0)
#define MM(ms_, ns_)                                                           \
  do {                                                                         \
    __builtin_amdgcn_s_setprio(1);                                             \
    _Pragma("unroll") for (int mq = 0; mq < 4; ++mq)                           \
      _Pragma("unroll") for (int nq = 0; nq < 2; ++nq)                         \
        _Pragma("unroll") for (int ks = 0; ks < 2; ++ks)                       \
          acc[(ms_) * 4 + mq][(ns_) * 2 + nq] =                                \
              __builtin_amdgcn_mfma_f32_16x16x32_bf16(                         \
                  af[mq][ks], bq[(ns_) * 2 + nq][ks],                          \
                  acc[(ms_) * 4 + mq][(ns_) * 2 + nq], 0, 0, 0);               \
    __builtin_amdgcn_s_setprio(0);                                             \
  } while (0)

  // ---- prologue: tile 0 (8 loads) + A0(1),B0(1) (4 loads); drain tile 0 ----
  STAGE_A(0, 0); STAGE_B(0, 0); STAGE_A(0, 1); STAGE_B(0, 1);
  STAGE_A(1, 0); STAGE_B(1, 0);
  asm volatile("s_waitcnt vmcnt(4)" ::: "memory");
  BAR();

  for (int t = 0; t < NT; ++t) {
    const int dcur = t & 1;
    const bool st1 = (t + 1 < NT), st2 = (t + 2 < NT);
    // ph0
    if (st1) { STAGE_B(t + 1, 1); STAGE_A(t + 1, 1); }
    RD_A(0); RD_B(0);
    BAR();
    MM(0, 0);
    // ph1
    RD_B(1);
    BAR();
    MM(0, 1);
    // ph2
    if (st2) STAGE_A(t + 2, 0);
    RD_A(1);
    BAR();
    MM(1, 0);
    // ph3
    if (st2) {
      STAGE_B(t + 2, 0);
      asm volatile("s_waitcnt vmcnt(4)" ::: "memory");
    } else {
      asm volatile("s_waitcnt vmcnt(0)" ::: "memory");
    }
    BAR();
    MM(1, 1);
  }
#undef GLD
#undef STAGE_A
#undef STAGE_B
#undef RD_A
#undef RD_B
#undef MM
#undef BAR

  // ---- epilogue: C/D layout col = li, row = kg*4 + j (m89-verified) ----
#pragma unroll
  for (int nf = 0; nf < 4; ++nf) {
    const int col = bCol + wc * 64 + nf * 16 + li;
    const float bv = bias[col];
#pragma unroll
    for (int mf = 0; mf < 8; ++mf) {
      const int row0 = bRow + wr * 128 + mf * 16 + kg * 4;
#pragma unroll
      for (int j = 0; j < 4; ++j)
        Y[(size_t)(row0 + j) * OUT_DIM + col] = acc[mf][nf][j] + bv;
    }
  }
}

extern "C" void kernel_launch(void* const* d_in, const int* in_sizes, int n_in,
                              void* d_out, int out_size, void* d_ws, size_t ws_size,
                              hipStream_t stream) {
  const float* x    = (const float*)d_in[0];
  const float* w    = (const float*)d_in[1];
  const float* bias = (const float*)d_in[2];
  const float* A    = (const float*)d_in[3];
  const float* B    = (const float*)d_in[4];
  float* y = (float*)d_out;

  const size_t xb_bytes = (size_t)M_DIM * IN_DIM * 2;          // 64 MiB
  const size_t wb_bytes = (size_t)OUT_DIM * IN_DIM * 2;        // 32 MiB
  if (ws_size < xb_bytes + wb_bytes) return;

  unsigned short* Xb = (unsigned short*)d_ws;
  unsigned short* Wb = (unsigned short*)((char*)d_ws + xb_bytes);

  prep_kernel<<<1536, 256, 0, stream>>>(x, Xb, w, A, B, Wb);
  gemm_kernel<<<(M_DIM / 256) * (OUT_DIM / 256), 512, 0, stream>>>(Xb, Wb, bias, y);
}